// Round 3
// baseline (1238.192 us; speedup 1.0000x reference)
//
#include <hip/hip_runtime.h>
#include <hip/hip_bf16.h>
#include <math.h>

#define N_NODES 50000
#define N_EDGES 800000
#define IN_DIM 128
#define HID_DIM 256
#define OUT_DIM 64
#define NPART 196            // ceil(N_NODES/256) coarse buckets (dst>>8)
#define CAP 8192             // static per-bucket capacity (mean 4096)
#define CHUNK 2048           // edges per partition block
#define NPB ((N_EDGES + CHUNK - 1) / CHUNK)   // 391 partition blocks

typedef __attribute__((ext_vector_type(8))) short bf16x8;
typedef __attribute__((ext_vector_type(4))) short short4v;
typedef __attribute__((ext_vector_type(4))) float f32x4;

__device__ inline short f2bf(float f) {   // round-to-nearest-even bf16
    unsigned u = __float_as_uint(f);
    unsigned r = (u + 0x7fffu + ((u >> 16) & 1u)) >> 16;
    return (short)r;
}
__device__ inline float bf_lo(unsigned u) { return __uint_as_float(u << 16); }
__device__ inline float bf_hi(unsigned u) { return __uint_as_float(u & 0xffff0000u); }

// ---- K1: blocks < NPB: LDS-staged coarse partition by dst>>8 (proven round-1 path)
// ----     + fire-and-forget per-node degree histogram (no return value -> pipelined)
// ---- blocks >= NPB: pack W1/W2 into MFMA B-frag bf16 order
__global__ __launch_bounds__(256) void part1_pack_kernel(const int* __restrict__ src,
                                                         const int* __restrict__ dst,
                                                         int* __restrict__ coarseCursor,
                                                         int* __restrict__ cntg,
                                                         uint2* __restrict__ sedge,
                                                         const float* __restrict__ W1,
                                                         const float* __restrict__ W2,
                                                         short* __restrict__ Bp1,
                                                         short* __restrict__ Bp2, int E) {
    __shared__ int cnt_l[NPART];
    __shared__ int pref[NPART];
    __shared__ int gbase[NPART];
    __shared__ int ws4[4];
    __shared__ uint2 stage[CHUNK];
    int tid = threadIdx.x;
    if (blockIdx.x >= NPB) {
        // ---- pack path ----
        int idx = (blockIdx.x - NPB) * 256 + tid;
        const float* W; short* Bp; int N;
        const int T1 = (IN_DIM / 32) * (HID_DIM / 16) * 64;    // 4096
        const int T2 = (HID_DIM / 32) * (OUT_DIM / 16) * 64;   // 2048
        if (idx < T1) { W = W1; Bp = Bp1; N = HID_DIM; }
        else { idx -= T1; if (idx >= T2) return; W = W2; Bp = Bp2; N = OUT_DIM; }
        int lane = idx & 63;
        int frag = idx >> 6;
        int ntiles = N >> 4;
        int nt = frag % ntiles;
        int kt = frag / ntiles;
        int col = nt * 16 + (lane & 15);
        int krow = kt * 32 + (lane >> 4) * 8;
        bf16x8 pk;
        #pragma unroll
        for (int j = 0; j < 8; j++) pk[j] = f2bf(W[(size_t)(krow + j) * N + col]);
        *((bf16x8*)(Bp + (size_t)idx * 8)) = pk;
        return;
    }
    int e0 = blockIdx.x * CHUNK;
    if (tid < NPART) cnt_l[tid] = 0;
    __syncthreads();
    int es[CHUNK / 256], ed[CHUNK / 256];
    #pragma unroll
    for (int j = 0; j < CHUNK / 256; j++) {
        int e = e0 + j * 256 + tid;
        if (e < E) {
            es[j] = src[e]; ed[j] = dst[e];
            atomicAdd(&cnt_l[ed[j] >> 8], 1);
            atomicAdd(&cntg[ed[j]], 1);          // fire-and-forget global degree
        } else ed[j] = -1;
    }
    __syncthreads();
    int lane = tid & 63, wid = tid >> 6;
    int v = (tid < NPART) ? cnt_l[tid] : 0;
    int s = v;
    #pragma unroll
    for (int off = 1; off < 64; off <<= 1) {
        int t = __shfl_up(s, off, 64);
        if (lane >= off) s += t;
    }
    if (lane == 63) ws4[wid] = s;
    __syncthreads();
    int wp = 0;
    #pragma unroll
    for (int w = 0; w < 4; w++) wp += (w < wid) ? ws4[w] : 0;
    int excl = s - v + wp;
    if (tid < NPART) pref[tid] = excl;
    __syncthreads();
    if (tid < NPART) cnt_l[tid] = excl;   // reuse as local cursor
    __syncthreads();
    #pragma unroll
    for (int j = 0; j < CHUNK / 256; j++) {
        if (ed[j] >= 0) {
            int c = ed[j] >> 8;
            int p = atomicAdd(&cnt_l[c], 1);
            stage[p] = make_uint2((unsigned)es[j], (unsigned)ed[j]);
        }
    }
    __syncthreads();
    if (tid < NPART) {
        int cl = cnt_l[tid] - pref[tid];
        gbase[tid] = (cl > 0) ? (tid * CAP + atomicAdd(&coarseCursor[tid], cl)) : 0;
    }
    __syncthreads();
    int total = (e0 + CHUNK <= E) ? CHUNK : (E - e0);
    for (int i = tid; i < total; i += 256) {
        uint2 ev = stage[i];
        int c = (int)(ev.y >> 8);
        sedge[gbase[c] + (i - pref[c])] = ev;
    }
}

// ---- K2 (196 blocks): dis = rsqrt(deg+1); xb = bf16(x * dis) -- no scan, no CSR ----
__global__ __launch_bounds__(256) void prep_kernel(const int* __restrict__ cntg,
                                                   float* __restrict__ dis,
                                                   const float* __restrict__ x,
                                                   short* __restrict__ xb, int n) {
    __shared__ float sdis[256];
    int b = blockIdx.x, tid = threadIdx.x;
    int nd = b * 256 + tid;
    int v = (nd < n) ? cntg[nd] : 0;
    float dn = rsqrtf((float)v + 1.0f);   // +1 self-loop
    if (nd < n) dis[nd] = dn;
    sdis[tid] = dn;
    __syncthreads();
    int rlane = tid & 31, rgrp = tid >> 5;
    for (int rb = 0; rb < 32; rb++) {
        int row = rb * 8 + rgrp;
        int nd2 = b * 256 + row;
        if (nd2 >= n) break;
        float d2 = sdis[row];
        float4 vv = ((const float4*)(x + (size_t)nd2 * IN_DIM))[rlane];
        short4v o = {f2bf(vv.x * d2), f2bf(vv.y * d2), f2bf(vv.z * d2), f2bf(vv.w * d2)};
        *((short4v*)(xb + (size_t)nd2 * IN_DIM + rlane * 4)) = o;
    }
}

// ---- K3: layer-1 aggregate, NO CSR. 2 blocks per bucket (dst bit 7 selects half).
// ---- LDS fp32 accumulator acc[128][128] (64 KB), fire-and-forget ds_add_f32.
// ---- Slot layout de-interleaved: feat 2l -> slot l, feat 2l+1 -> slot 64+l
// ---- (stride-4B per add across the wave -> 2-way bank aliasing only, free).
__global__ __launch_bounds__(512) void agg1B_kernel(const short* __restrict__ xb,
                                                    const uint2* __restrict__ sedge,
                                                    const int* __restrict__ coarseCnt,
                                                    const float* __restrict__ dis,
                                                    short* __restrict__ aggx, int n) {
    __shared__ float acc[128 * 128];
    int tid = threadIdx.x;
    int b = blockIdx.x >> 1;
    unsigned half = blockIdx.x & 1;
    int base = b * CAP;
    int cb = coarseCnt[b];
    float4* a4 = (float4*)acc;
    for (int s = tid; s < 128 * 32; s += 512) a4[s] = make_float4(0.f, 0.f, 0.f, 0.f);
    __syncthreads();
    int lane = tid & 63, wid = tid >> 6;   // 8 waves
    const unsigned* xbu = (const unsigned*)xb;
    int i = wid;
    for (; i + 8 < cb; i += 16) {
        uint2 e0 = sedge[base + i];
        uint2 e1 = sedge[base + i + 8];
        bool o0 = ((e0.y >> 7) & 1u) == half;
        bool o1 = ((e1.y >> 7) & 1u) == half;
        unsigned u0 = 0, u1 = 0;
        if (o0) u0 = xbu[(size_t)e0.x * (IN_DIM / 2) + lane];
        if (o1) u1 = xbu[(size_t)e1.x * (IN_DIM / 2) + lane];
        if (o0) {
            int r = (int)(e0.y & 127u) * 128;
            atomicAdd(&acc[r + lane], bf_lo(u0));
            atomicAdd(&acc[r + 64 + lane], bf_hi(u0));
        }
        if (o1) {
            int r = (int)(e1.y & 127u) * 128;
            atomicAdd(&acc[r + lane], bf_lo(u1));
            atomicAdd(&acc[r + 64 + lane], bf_hi(u1));
        }
    }
    for (; i < cb; i += 8) {
        uint2 e0 = sedge[base + i];
        if (((e0.y >> 7) & 1u) == half) {
            unsigned u0 = xbu[(size_t)e0.x * (IN_DIM / 2) + lane];
            int r = (int)(e0.y & 127u) * 128;
            atomicAdd(&acc[r + lane], bf_lo(u0));
            atomicAdd(&acc[r + 64 + lane], bf_hi(u0));
        }
    }
    __syncthreads();
    // epilogue: + self-loop, * dis, pack bf16 pair, store u32 (coalesced)
    unsigned* aggxu = (unsigned*)aggx;
    for (int s = tid; s < 128 * 64; s += 512) {
        int r = s >> 6, cp = s & 63;
        int nd = b * 256 + (int)half * 128 + r;
        if (nd >= n) continue;
        float dn = dis[nd];
        unsigned us = xbu[(size_t)nd * (IN_DIM / 2) + cp];
        float v0 = (acc[r * 128 + cp] + bf_lo(us)) * dn;
        float v1 = (acc[r * 128 + 64 + cp] + bf_hi(us)) * dn;
        aggxu[(size_t)nd * (IN_DIM / 2) + cp] =
            ((unsigned)(unsigned short)f2bf(v1) << 16) | (unsigned)(unsigned short)f2bf(v0);
    }
}

// -------- fused MFMA GEMM: h2[r,:] = dis[r] * (relu(aggx[r,:]@W1 + b1) @ W2) ----------
#define H1_STRIDE 264
__global__ __launch_bounds__(256) void gemm_fused_kernel(const short* __restrict__ A,
                                                         const short* __restrict__ Bp1,
                                                         const short* __restrict__ Bp2,
                                                         const float* __restrict__ b1,
                                                         const float* __restrict__ dis,
                                                         short* __restrict__ h2, int M) {
    __shared__ short lds_h1[4][16][H1_STRIDE];
    int lane = threadIdx.x & 63;
    int w = threadIdx.x >> 6;
    int rowBase = blockIdx.x * 64 + w * 16;
    int arow = rowBase + (lane & 15);
    int kseg = lane >> 4;             // 0..3
    int col0 = lane & 15;

    // ---- phase A: h1 = relu(aggx @ W1 + b1), K=128, N=256 ----
    constexpr int NT1 = HID_DIM / 16;   // 16
    f32x4 acc1[NT1] = {};
    #pragma unroll
    for (int kt = 0; kt < IN_DIM / 32; kt++) {
        bf16x8 a = {};
        if (arow < M)
            a = *((const bf16x8*)(A + (size_t)arow * IN_DIM + kt * 32 + kseg * 8));
        #pragma unroll
        for (int nt = 0; nt < NT1; nt++) {
            bf16x8 b = *((const bf16x8*)(Bp1 + ((size_t)(kt * NT1 + nt) * 64 + lane) * 8));
            acc1[nt] = __builtin_amdgcn_mfma_f32_16x16x32_bf16(a, b, acc1[nt], 0, 0, 0);
        }
    }
    #pragma unroll
    for (int nt = 0; nt < NT1; nt++) {
        float bv = b1[nt * 16 + col0];
        #pragma unroll
        for (int i = 0; i < 4; i++) {
            float v = fmaxf(acc1[nt][i] + bv, 0.0f);
            lds_h1[w][kseg * 4 + i][nt * 16 + col0] = f2bf(v);
        }
    }
    // ---- phase B: h2 = (h1 @ W2) * dis, K=256, N=64; A-frags from own wave's LDS ----
    constexpr int NT2 = OUT_DIM / 16;   // 4
    f32x4 acc2[NT2] = {};
    #pragma unroll
    for (int kt = 0; kt < HID_DIM / 32; kt++) {
        bf16x8 a = *((const bf16x8*)&lds_h1[w][lane & 15][kt * 32 + kseg * 8]);
        #pragma unroll
        for (int nt = 0; nt < NT2; nt++) {
            bf16x8 b = *((const bf16x8*)(Bp2 + ((size_t)(kt * NT2 + nt) * 64 + lane) * 8));
            acc2[nt] = __builtin_amdgcn_mfma_f32_16x16x32_bf16(a, b, acc2[nt], 0, 0, 0);
        }
    }
    #pragma unroll
    for (int i = 0; i < 4; i++) {
        int r = rowBase + kseg * 4 + i;
        if (r >= M) continue;
        float sc = dis[r];
        #pragma unroll
        for (int nt = 0; nt < NT2; nt++)
            h2[(size_t)r * OUT_DIM + nt * 16 + col0] = f2bf(acc2[nt][i] * sc);
    }
}

// ---- K5: layer-2 aggregate, NO CSR. Same bucket-LDS scheme, acc[128][64] (32 KB).
// ---- Lane owns one feature (stride-4B adds, 2-way aliasing only).
// ---- Epilogue: self-loop + bias + log_softmax, wave per row (lane = column).
__global__ __launch_bounds__(512) void agg2B_kernel(const short* __restrict__ h2,
                                                    const uint2* __restrict__ sedge,
                                                    const int* __restrict__ coarseCnt,
                                                    const float* __restrict__ dis,
                                                    const float* __restrict__ b2,
                                                    float* __restrict__ out, int n) {
    __shared__ float acc[128 * 64];
    int tid = threadIdx.x;
    int b = blockIdx.x >> 1;
    unsigned half = blockIdx.x & 1;
    int base = b * CAP;
    int cb = coarseCnt[b];
    float4* a4 = (float4*)acc;
    for (int s = tid; s < 128 * 16; s += 512) a4[s] = make_float4(0.f, 0.f, 0.f, 0.f);
    __syncthreads();
    int lane = tid & 63, wid = tid >> 6;
    const unsigned short* h2u = (const unsigned short*)h2;
    int i = wid;
    for (; i + 8 < cb; i += 16) {
        uint2 e0 = sedge[base + i];
        uint2 e1 = sedge[base + i + 8];
        bool o0 = ((e0.y >> 7) & 1u) == half;
        bool o1 = ((e1.y >> 7) & 1u) == half;
        unsigned short u0 = 0, u1 = 0;
        if (o0) u0 = h2u[(size_t)e0.x * OUT_DIM + lane];
        if (o1) u1 = h2u[(size_t)e1.x * OUT_DIM + lane];
        if (o0) atomicAdd(&acc[(int)(e0.y & 127u) * 64 + lane], __uint_as_float((unsigned)u0 << 16));
        if (o1) atomicAdd(&acc[(int)(e1.y & 127u) * 64 + lane], __uint_as_float((unsigned)u1 << 16));
    }
    for (; i < cb; i += 8) {
        uint2 e0 = sedge[base + i];
        if (((e0.y >> 7) & 1u) == half) {
            unsigned short u0 = h2u[(size_t)e0.x * OUT_DIM + lane];
            atomicAdd(&acc[(int)(e0.y & 127u) * 64 + lane], __uint_as_float((unsigned)u0 << 16));
        }
    }
    __syncthreads();
    // epilogue: wave per row
    for (int r = wid; r < 128; r += 8) {
        int nd = b * 256 + (int)half * 128 + r;
        if (nd >= n) continue;
        float dn = dis[nd];
        unsigned short us = h2u[(size_t)nd * OUT_DIM + lane];
        float a = (acc[r * 64 + lane] + __uint_as_float((unsigned)us << 16)) * dn + b2[lane];
        float m = a;
        #pragma unroll
        for (int off = 1; off < 64; off <<= 1) m = fmaxf(m, __shfl_xor(m, off, 64));
        float e = expf(a - m);
        float sum = e;
        #pragma unroll
        for (int off = 1; off < 64; off <<= 1) sum += __shfl_xor(sum, off, 64);
        out[(size_t)nd * OUT_DIM + lane] = a - m - logf(sum);
    }
}

extern "C" void kernel_launch(void* const* d_in, const int* in_sizes, int n_in,
                              void* d_out, int out_size, void* d_ws, size_t ws_size,
                              hipStream_t stream) {
    const float* x  = (const float*)d_in[0];
    const int*   ei = (const int*)d_in[1];
    const float* W1 = (const float*)d_in[2];
    const float* b1 = (const float*)d_in[3];
    const float* W2 = (const float*)d_in[4];
    const float* b2 = (const float*)d_in[5];
    float* out = (float*)d_out;
    char* ws = (char*)d_ws;

    const int* srcp = ei;
    const int* dstp = ei + N_EDGES;

    // workspace layout (256-aligned)
    int*   coarseCursor = (int*)(ws);              // 196 int (becomes per-bucket count)
    int*   cntg   = (int*)(ws + 1024);             // 50000 int (degree)
    float* dis    = (float*)(ws + 204800);         // 50000 f32
    short* Bp1    = (short*)(ws + 409600);         // 64 KB packed W1
    short* Bp2    = (short*)(ws + 475136);         // 32 KB packed W2
    uint2* sedge  = (uint2*)(ws + 524288);         // 196*8192*8 = 12.85 MB (live to end)
    short* xb     = (short*)(ws + 13369344);       // 12.8 MB bf16 x*dis
    short* aggx   = (short*)(ws + 26169344);       // 12.8 MB bf16
    short* h2     = (short*)(ws + 38969344);       // 6.4 MB bf16

    // one memset covers coarseCursor + cntg (adjacent)
    hipMemsetAsync(ws, 0, 1024 + N_NODES * 4, stream);

    part1_pack_kernel<<<NPB + 24, 256, 0, stream>>>(srcp, dstp, coarseCursor, cntg, sedge,
                                                    W1, W2, Bp1, Bp2, N_EDGES);
    prep_kernel<<<NPART, 256, 0, stream>>>(cntg, dis, x, xb, N_NODES);
    agg1B_kernel<<<NPART * 2, 512, 0, stream>>>(xb, sedge, coarseCursor, dis, aggx, N_NODES);
    gemm_fused_kernel<<<(N_NODES + 63) / 64, 256, 0, stream>>>(aggx, Bp1, Bp2, b1, dis,
                                                               h2, N_NODES);
    agg2B_kernel<<<NPART * 2, 512, 0, stream>>>(h2, sedge, coarseCursor, dis, b2, out, N_NODES);
}

// Round 4
// 218.550 us; speedup vs baseline: 5.6655x; 5.6655x over previous
//
#include <hip/hip_runtime.h>
#include <hip/hip_bf16.h>
#include <math.h>

#define N_NODES 50000
#define N_EDGES 800000
#define IN_DIM 128
#define HID_DIM 256
#define OUT_DIM 64
#define NPART 196            // ceil(N_NODES/256) coarse buckets (dst>>8)
#define CAP 8192             // static per-bucket capacity (mean 4096)
#define CHUNK 2048           // edges per partition block
#define NPB ((N_EDGES + CHUNK - 1) / CHUNK)   // 391 partition blocks
#define NPACK 24             // W-pack blocks
#define NPREP NPART          // xb-convert blocks

typedef __attribute__((ext_vector_type(8))) short bf16x8;
typedef __attribute__((ext_vector_type(4))) short short4v;
typedef __attribute__((ext_vector_type(4))) float f32x4;

__device__ inline short f2bf(float f) {   // round-to-nearest-even bf16
    unsigned u = __float_as_uint(f);
    unsigned r = (u + 0x7fffu + ((u >> 16) & 1u)) >> 16;
    return (short)r;
}
__device__ inline float bf_lo(unsigned u) { return __uint_as_float(u << 16); }
__device__ inline float bf_hi(unsigned u) { return __uint_as_float(u & 0xffff0000u); }

// ---- K1: three block roles in one launch (co-scheduled so streaming prep blocks
// ---- overlap the latency-bound partition blocks):
// ----   bid < NPB:               LDS-staged coarse partition by dst>>8 (round-0 proven)
// ----                            + fire-and-forget per-node degree histogram
// ----   NPB <= bid < NPB+NPACK:  pack W1/W2 into MFMA B-frag bf16 order
// ----   bid >= NPB+NPACK:        xb = bf16(x) UNSCALED (dis applied later in agg1)
__global__ __launch_bounds__(256) void part1_pack_prep_kernel(const int* __restrict__ src,
                                                              const int* __restrict__ dst,
                                                              int* __restrict__ coarseCursor,
                                                              int* __restrict__ cntg,
                                                              uint2* __restrict__ sedge,
                                                              const float* __restrict__ W1,
                                                              const float* __restrict__ W2,
                                                              short* __restrict__ Bp1,
                                                              short* __restrict__ Bp2,
                                                              const float* __restrict__ x,
                                                              short* __restrict__ xb, int E) {
    __shared__ int cnt_l[NPART];
    __shared__ int pref[NPART];
    __shared__ int gbase[NPART];
    __shared__ int ws4[4];
    __shared__ uint2 stage[CHUNK];
    int tid = threadIdx.x;
    if (blockIdx.x >= NPB + NPACK) {
        // ---- prep path: xb[nd,:] = bf16(x[nd,:]), coalesced, no scaling ----
        int pb = blockIdx.x - NPB - NPACK;
        int rlane = tid & 31, rgrp = tid >> 5;
        for (int rb = 0; rb < 32; rb++) {
            int row = rb * 8 + rgrp;
            int nd = pb * 256 + row;
            if (nd >= N_NODES) break;
            float4 vv = ((const float4*)(x + (size_t)nd * IN_DIM))[rlane];
            short4v o = {f2bf(vv.x), f2bf(vv.y), f2bf(vv.z), f2bf(vv.w)};
            *((short4v*)(xb + (size_t)nd * IN_DIM + rlane * 4)) = o;
        }
        return;
    }
    if (blockIdx.x >= NPB) {
        // ---- pack path ----
        int idx = (blockIdx.x - NPB) * 256 + tid;
        const float* W; short* Bp; int N;
        const int T1 = (IN_DIM / 32) * (HID_DIM / 16) * 64;    // 4096
        const int T2 = (HID_DIM / 32) * (OUT_DIM / 16) * 64;   // 2048
        if (idx < T1) { W = W1; Bp = Bp1; N = HID_DIM; }
        else { idx -= T1; if (idx >= T2) return; W = W2; Bp = Bp2; N = OUT_DIM; }
        int lane = idx & 63;
        int frag = idx >> 6;
        int ntiles = N >> 4;
        int nt = frag % ntiles;
        int kt = frag / ntiles;
        int col = nt * 16 + (lane & 15);
        int krow = kt * 32 + (lane >> 4) * 8;
        bf16x8 pk;
        #pragma unroll
        for (int j = 0; j < 8; j++) pk[j] = f2bf(W[(size_t)(krow + j) * N + col]);
        *((bf16x8*)(Bp + (size_t)idx * 8)) = pk;
        return;
    }
    // ---- partition path (round-0 proven) ----
    int e0 = blockIdx.x * CHUNK;
    if (tid < NPART) cnt_l[tid] = 0;
    __syncthreads();
    int es[CHUNK / 256], ed[CHUNK / 256];
    #pragma unroll
    for (int j = 0; j < CHUNK / 256; j++) {
        int e = e0 + j * 256 + tid;
        if (e < E) {
            es[j] = src[e]; ed[j] = dst[e];
            atomicAdd(&cnt_l[ed[j] >> 8], 1);
            atomicAdd(&cntg[ed[j]], 1);          // fire-and-forget degree (pipelined)
        } else ed[j] = -1;
    }
    __syncthreads();
    int lane = tid & 63, wid = tid >> 6;
    int v = (tid < NPART) ? cnt_l[tid] : 0;
    int s = v;
    #pragma unroll
    for (int off = 1; off < 64; off <<= 1) {
        int t = __shfl_up(s, off, 64);
        if (lane >= off) s += t;
    }
    if (lane == 63) ws4[wid] = s;
    __syncthreads();
    int wp = 0;
    #pragma unroll
    for (int w = 0; w < 4; w++) wp += (w < wid) ? ws4[w] : 0;
    int excl = s - v + wp;
    if (tid < NPART) pref[tid] = excl;
    __syncthreads();
    if (tid < NPART) cnt_l[tid] = excl;   // reuse as local cursor
    __syncthreads();
    #pragma unroll
    for (int j = 0; j < CHUNK / 256; j++) {
        if (ed[j] >= 0) {
            int c = ed[j] >> 8;
            int p = atomicAdd(&cnt_l[c], 1);
            stage[p] = make_uint2((unsigned)es[j], (unsigned)ed[j]);
        }
    }
    __syncthreads();
    if (tid < NPART) {
        int cl = cnt_l[tid] - pref[tid];
        gbase[tid] = (cl > 0) ? (tid * CAP + atomicAdd(&coarseCursor[tid], cl)) : 0;
    }
    __syncthreads();
    int total = (e0 + CHUNK <= E) ? CHUNK : (E - e0);
    for (int i = tid; i < total; i += 256) {
        uint2 ev = stage[i];
        int c = (int)(ev.y >> 8);
        sedge[gbase[c] + (i - pref[c])] = ev;
    }
}

// ---- K2 (196 blocks): scan degrees (from histogram, NO counting pass over sedge),
// ---- one scatter pass sedge -> ssrc via LDS cursors, and dis = rsqrt(deg+1).
__global__ __launch_bounds__(256) void part2_kernel(const uint2* __restrict__ sedge,
                                                    const int* __restrict__ coarseCnt,
                                                    const int* __restrict__ cntg,
                                                    int* __restrict__ offs,
                                                    float* __restrict__ dis,
                                                    int* __restrict__ ssrc, int n) {
    __shared__ int kcnt[256];
    __shared__ int ws4[4];
    int b = blockIdx.x, tid = threadIdx.x;
    int base = b * CAP;
    int cb = coarseCnt[b];
    int nd = b * 256 + tid;
    int v = (nd < n) ? cntg[nd] : 0;
    int lane = tid & 63, wid = tid >> 6;
    int s = v;
    #pragma unroll
    for (int off = 1; off < 64; off <<= 1) {
        int t = __shfl_up(s, off, 64);
        if (lane >= off) s += t;
    }
    if (lane == 63) ws4[wid] = s;
    __syncthreads();
    int wp = 0;
    #pragma unroll
    for (int w = 0; w < 4; w++) wp += (w < wid) ? ws4[w] : 0;
    int excl = s - v + wp;
    if (nd < n) {
        offs[nd] = base + excl;
        dis[nd] = rsqrtf((float)v + 1.0f);   // +1 self-loop
    }
    kcnt[tid] = base + excl;              // LDS cursor
    __syncthreads();
    for (int i = tid; i < cb; i += 256) {
        uint2 ev = sedge[base + i];
        int pos = atomicAdd(&kcnt[ev.y & 255], 1);
        ssrc[pos] = (int)ev.x;
    }
}

// ------- layer-1 aggregate (round-0 proven structure): wave per node, 8 groups x 8
// ------- lanes (32 B/lane/row), 16 row-gathers in flight per wave. Gate multiplier
// ------- now carries dis[src] (xb is unscaled); self-loop weighted by dis[node].
__global__ void agg1_kernel(const short* __restrict__ xb, const int* __restrict__ ssrc,
                            const int* __restrict__ offs, const int* __restrict__ cnt,
                            const float* __restrict__ dis, short* __restrict__ aggx, int n) {
    int lane = threadIdx.x & 63;
    int node = blockIdx.x * 4 + (threadIdx.x >> 6);
    if (node >= n) return;
    int grp = lane >> 3, l8 = lane & 7;
    int start = offs[node], c = cnt[node];
    int vidx = (lane < c) ? ssrc[start + lane] : 0;   // all indices in one coalesced load
    float acc[16] = {};
    int lim = (c < 64) ? c : 64;
    int rounds = (lim + 15) >> 4;                     // wave-uniform trip count
    for (int r = 0; r < rounds; r++) {
        int j0 = r * 16 + grp;
        int j1 = j0 + 8;
        int i0 = (j0 < 63) ? j0 : 63;                 // clamp: shuffle index always valid
        int i1 = (j1 < 63) ? j1 : 63;
        int s0 = __shfl(vidx, i0, 64);
        int s1 = __shfl(vidx, i1, 64);
        float g0 = (j0 < lim) ? dis[s0] : 0.0f;       // per-edge norm as the gate weight
        float g1 = (j1 < lim) ? dis[s1] : 0.0f;
        const uint4* r0 = (const uint4*)(xb + (size_t)s0 * IN_DIM + l8 * 16);
        const uint4* r1 = (const uint4*)(xb + (size_t)s1 * IN_DIM + l8 * 16);
        uint4 a0 = r0[0], a1 = r0[1];
        uint4 b0 = r1[0], b1 = r1[1];
        acc[0]  += g0 * bf_lo(a0.x); acc[1]  += g0 * bf_hi(a0.x);
        acc[2]  += g0 * bf_lo(a0.y); acc[3]  += g0 * bf_hi(a0.y);
        acc[4]  += g0 * bf_lo(a0.z); acc[5]  += g0 * bf_hi(a0.z);
        acc[6]  += g0 * bf_lo(a0.w); acc[7]  += g0 * bf_hi(a0.w);
        acc[8]  += g0 * bf_lo(a1.x); acc[9]  += g0 * bf_hi(a1.x);
        acc[10] += g0 * bf_lo(a1.y); acc[11] += g0 * bf_hi(a1.y);
        acc[12] += g0 * bf_lo(a1.z); acc[13] += g0 * bf_hi(a1.z);
        acc[14] += g0 * bf_lo(a1.w); acc[15] += g0 * bf_hi(a1.w);
        acc[0]  += g1 * bf_lo(b0.x); acc[1]  += g1 * bf_hi(b0.x);
        acc[2]  += g1 * bf_lo(b0.y); acc[3]  += g1 * bf_hi(b0.y);
        acc[4]  += g1 * bf_lo(b0.z); acc[5]  += g1 * bf_hi(b0.z);
        acc[6]  += g1 * bf_lo(b0.w); acc[7]  += g1 * bf_hi(b0.w);
        acc[8]  += g1 * bf_lo(b1.x); acc[9]  += g1 * bf_hi(b1.x);
        acc[10] += g1 * bf_lo(b1.y); acc[11] += g1 * bf_hi(b1.y);
        acc[12] += g1 * bf_lo(b1.z); acc[13] += g1 * bf_hi(b1.z);
        acc[14] += g1 * bf_lo(b1.w); acc[15] += g1 * bf_hi(b1.w);
    }
    // rare tail c > 64: per-lane global index loads, no shuffles
    for (int j = 64 + grp; j < c; j += 8) {
        int s0 = ssrc[start + j];
        float w0 = dis[s0];
        const uint4* r0 = (const uint4*)(xb + (size_t)s0 * IN_DIM + l8 * 16);
        uint4 a0 = r0[0], a1 = r0[1];
        acc[0]  += w0 * bf_lo(a0.x); acc[1]  += w0 * bf_hi(a0.x);
        acc[2]  += w0 * bf_lo(a0.y); acc[3]  += w0 * bf_hi(a0.y);
        acc[4]  += w0 * bf_lo(a0.z); acc[5]  += w0 * bf_hi(a0.z);
        acc[6]  += w0 * bf_lo(a0.w); acc[7]  += w0 * bf_hi(a0.w);
        acc[8]  += w0 * bf_lo(a1.x); acc[9]  += w0 * bf_hi(a1.x);
        acc[10] += w0 * bf_lo(a1.y); acc[11] += w0 * bf_hi(a1.y);
        acc[12] += w0 * bf_lo(a1.z); acc[13] += w0 * bf_hi(a1.z);
        acc[14] += w0 * bf_lo(a1.w); acc[15] += w0 * bf_hi(a1.w);
    }
    #pragma unroll
    for (int k = 0; k < 16; k++) {
        acc[k] += __shfl_xor(acc[k], 8, 64);
        acc[k] += __shfl_xor(acc[k], 16, 64);
        acc[k] += __shfl_xor(acc[k], 32, 64);
    }
    if (grp == 0) {
        float dn = dis[node];
        const uint4* rs = (const uint4*)(xb + (size_t)node * IN_DIM + l8 * 16);
        uint4 a0 = rs[0], a1 = rs[1];
        acc[0]  += dn * bf_lo(a0.x); acc[1]  += dn * bf_hi(a0.x);
        acc[2]  += dn * bf_lo(a0.y); acc[3]  += dn * bf_hi(a0.y);
        acc[4]  += dn * bf_lo(a0.z); acc[5]  += dn * bf_hi(a0.z);
        acc[6]  += dn * bf_lo(a0.w); acc[7]  += dn * bf_hi(a0.w);
        acc[8]  += dn * bf_lo(a1.x); acc[9]  += dn * bf_hi(a1.x);
        acc[10] += dn * bf_lo(a1.y); acc[11] += dn * bf_hi(a1.y);
        acc[12] += dn * bf_lo(a1.z); acc[13] += dn * bf_hi(a1.z);
        acc[14] += dn * bf_lo(a1.w); acc[15] += dn * bf_hi(a1.w);
        bf16x8 o0, o1;
        #pragma unroll
        for (int k = 0; k < 8; k++) { o0[k] = f2bf(acc[k] * dn); o1[k] = f2bf(acc[k + 8] * dn); }
        short* dst0 = aggx + (size_t)node * IN_DIM + l8 * 16;
        *((bf16x8*)dst0) = o0;
        *((bf16x8*)(dst0 + 8)) = o1;
    }
}

// -------- fused MFMA GEMM: h2[r,:] = dis[r] * (relu(aggx[r,:]@W1 + b1) @ W2) ----------
#define H1_STRIDE 264
__global__ __launch_bounds__(256) void gemm_fused_kernel(const short* __restrict__ A,
                                                         const short* __restrict__ Bp1,
                                                         const short* __restrict__ Bp2,
                                                         const float* __restrict__ b1,
                                                         const float* __restrict__ dis,
                                                         short* __restrict__ h2, int M) {
    __shared__ short lds_h1[4][16][H1_STRIDE];
    int lane = threadIdx.x & 63;
    int w = threadIdx.x >> 6;
    int rowBase = blockIdx.x * 64 + w * 16;
    int arow = rowBase + (lane & 15);
    int kseg = lane >> 4;             // 0..3
    int col0 = lane & 15;

    // ---- phase A: h1 = relu(aggx @ W1 + b1), K=128, N=256 ----
    constexpr int NT1 = HID_DIM / 16;   // 16
    f32x4 acc1[NT1] = {};
    #pragma unroll
    for (int kt = 0; kt < IN_DIM / 32; kt++) {
        bf16x8 a = {};
        if (arow < M)
            a = *((const bf16x8*)(A + (size_t)arow * IN_DIM + kt * 32 + kseg * 8));
        #pragma unroll
        for (int nt = 0; nt < NT1; nt++) {
            bf16x8 b = *((const bf16x8*)(Bp1 + ((size_t)(kt * NT1 + nt) * 64 + lane) * 8));
            acc1[nt] = __builtin_amdgcn_mfma_f32_16x16x32_bf16(a, b, acc1[nt], 0, 0, 0);
        }
    }
    #pragma unroll
    for (int nt = 0; nt < NT1; nt++) {
        float bv = b1[nt * 16 + col0];
        #pragma unroll
        for (int i = 0; i < 4; i++) {
            float v = fmaxf(acc1[nt][i] + bv, 0.0f);
            lds_h1[w][kseg * 4 + i][nt * 16 + col0] = f2bf(v);
        }
    }
    // ---- phase B: h2 = (h1 @ W2) * dis, K=256, N=64; A-frags from own wave's LDS ----
    constexpr int NT2 = OUT_DIM / 16;   // 4
    f32x4 acc2[NT2] = {};
    #pragma unroll
    for (int kt = 0; kt < HID_DIM / 32; kt++) {
        bf16x8 a = *((const bf16x8*)&lds_h1[w][lane & 15][kt * 32 + kseg * 8]);
        #pragma unroll
        for (int nt = 0; nt < NT2; nt++) {
            bf16x8 b = *((const bf16x8*)(Bp2 + ((size_t)(kt * NT2 + nt) * 64 + lane) * 8));
            acc2[nt] = __builtin_amdgcn_mfma_f32_16x16x32_bf16(a, b, acc2[nt], 0, 0, 0);
        }
    }
    #pragma unroll
    for (int i = 0; i < 4; i++) {
        int r = rowBase + kseg * 4 + i;
        if (r >= M) continue;
        float sc = dis[r];
        #pragma unroll
        for (int nt = 0; nt < NT2; nt++)
            h2[(size_t)r * OUT_DIM + nt * 16 + col0] = f2bf(acc2[nt][i] * sc);
    }
}

// ------- layer-2 aggregate (round-0 proven): wave per node, 8 groups x 8 lanes
// ------- (16 B/lane/row), wave-uniform shuffle rounds, + self-loop + bias + log_softmax
__global__ void agg2_kernel(const short* __restrict__ h2, const int* __restrict__ ssrc,
                            const int* __restrict__ offs, const int* __restrict__ cnt,
                            const float* __restrict__ dis, const float* __restrict__ b2,
                            float* __restrict__ out, int n) {
    int lane = threadIdx.x & 63;
    int node = blockIdx.x * 4 + (threadIdx.x >> 6);
    if (node >= n) return;
    int grp = lane >> 3, l8 = lane & 7;
    int start = offs[node], c = cnt[node];
    int vidx = (lane < c) ? ssrc[start + lane] : 0;
    float acc[8] = {};
    int lim = (c < 64) ? c : 64;
    int rounds = (lim + 15) >> 4;                     // wave-uniform
    for (int r = 0; r < rounds; r++) {
        int j0 = r * 16 + grp;
        int j1 = j0 + 8;
        int i0 = (j0 < 63) ? j0 : 63;
        int i1 = (j1 < 63) ? j1 : 63;
        int s0 = __shfl(vidx, i0, 64);
        int s1 = __shfl(vidx, i1, 64);
        float g0 = (j0 < lim) ? 1.0f : 0.0f;
        float g1 = (j1 < lim) ? 1.0f : 0.0f;
        uint4 p0 = *((const uint4*)(h2 + (size_t)s0 * OUT_DIM + l8 * 8));
        uint4 p1 = *((const uint4*)(h2 + (size_t)s1 * OUT_DIM + l8 * 8));
        acc[0] += g0 * bf_lo(p0.x); acc[1] += g0 * bf_hi(p0.x);
        acc[2] += g0 * bf_lo(p0.y); acc[3] += g0 * bf_hi(p0.y);
        acc[4] += g0 * bf_lo(p0.z); acc[5] += g0 * bf_hi(p0.z);
        acc[6] += g0 * bf_lo(p0.w); acc[7] += g0 * bf_hi(p0.w);
        acc[0] += g1 * bf_lo(p1.x); acc[1] += g1 * bf_hi(p1.x);
        acc[2] += g1 * bf_lo(p1.y); acc[3] += g1 * bf_hi(p1.y);
        acc[4] += g1 * bf_lo(p1.z); acc[5] += g1 * bf_hi(p1.z);
        acc[6] += g1 * bf_lo(p1.w); acc[7] += g1 * bf_hi(p1.w);
    }
    // rare tail c > 64
    for (int j = 64 + grp; j < c; j += 8) {
        int s0 = ssrc[start + j];
        uint4 p0 = *((const uint4*)(h2 + (size_t)s0 * OUT_DIM + l8 * 8));
        acc[0] += bf_lo(p0.x); acc[1] += bf_hi(p0.x); acc[2] += bf_lo(p0.y); acc[3] += bf_hi(p0.y);
        acc[4] += bf_lo(p0.z); acc[5] += bf_hi(p0.z); acc[6] += bf_lo(p0.w); acc[7] += bf_hi(p0.w);
    }
    #pragma unroll
    for (int k = 0; k < 8; k++) {
        acc[k] += __shfl_xor(acc[k], 8, 64);
        acc[k] += __shfl_xor(acc[k], 16, 64);
        acc[k] += __shfl_xor(acc[k], 32, 64);
    }
    // self-loop + dn scale + bias (cols l8*8 .. l8*8+7)
    float dn = dis[node];
    uint4 pv = *((const uint4*)(h2 + (size_t)node * OUT_DIM + l8 * 8));
    float4 bb0 = ((const float4*)b2)[l8 * 2];
    float4 bb1 = ((const float4*)b2)[l8 * 2 + 1];
    acc[0] = (acc[0] + bf_lo(pv.x)) * dn + bb0.x;
    acc[1] = (acc[1] + bf_hi(pv.x)) * dn + bb0.y;
    acc[2] = (acc[2] + bf_lo(pv.y)) * dn + bb0.z;
    acc[3] = (acc[3] + bf_hi(pv.y)) * dn + bb0.w;
    acc[4] = (acc[4] + bf_lo(pv.z)) * dn + bb1.x;
    acc[5] = (acc[5] + bf_hi(pv.z)) * dn + bb1.y;
    acc[6] = (acc[6] + bf_lo(pv.w)) * dn + bb1.z;
    acc[7] = (acc[7] + bf_hi(pv.w)) * dn + bb1.w;
    // log_softmax over 64 cols (8 l8-lanes x 8 regs)
    float m = acc[0];
    #pragma unroll
    for (int k = 1; k < 8; k++) m = fmaxf(m, acc[k]);
    #pragma unroll
    for (int off = 1; off < 8; off <<= 1) m = fmaxf(m, __shfl_xor(m, off, 64));
    float ex = 0.0f;
    #pragma unroll
    for (int k = 0; k < 8; k++) ex += expf(acc[k] - m);
    #pragma unroll
    for (int off = 1; off < 8; off <<= 1) ex += __shfl_xor(ex, off, 64);
    float ls = m + logf(ex);
    if (grp == 0) {
        float4 o0 = {acc[0] - ls, acc[1] - ls, acc[2] - ls, acc[3] - ls};
        float4 o1 = {acc[4] - ls, acc[5] - ls, acc[6] - ls, acc[7] - ls};
        ((float4*)(out + (size_t)node * OUT_DIM))[l8 * 2] = o0;
        ((float4*)(out + (size_t)node * OUT_DIM))[l8 * 2 + 1] = o1;
    }
}

extern "C" void kernel_launch(void* const* d_in, const int* in_sizes, int n_in,
                              void* d_out, int out_size, void* d_ws, size_t ws_size,
                              hipStream_t stream) {
    const float* x  = (const float*)d_in[0];
    const int*   ei = (const int*)d_in[1];
    const float* W1 = (const float*)d_in[2];
    const float* b1 = (const float*)d_in[3];
    const float* W2 = (const float*)d_in[4];
    const float* b2 = (const float*)d_in[5];
    float* out = (float*)d_out;
    char* ws = (char*)d_ws;

    const int* srcp = ei;
    const int* dstp = ei + N_EDGES;

    // workspace layout (256-aligned)
    int*   coarseCursor = (int*)(ws);              // 196 int (becomes per-bucket count)
    int*   cntg   = (int*)(ws + 1024);             // 50000 int degree (also agg cnt)
    int*   offs   = (int*)(ws + 204800);           // 50000 int
    float* dis    = (float*)(ws + 409600);         // 50000 f32
    short* Bp1    = (short*)(ws + 614400);         // 64 KB packed W1
    short* Bp2    = (short*)(ws + 679936);         // 32 KB packed W2
    int*   ssrc   = (int*)(ws + 720896);           // 196*8192*4 = 6.4 MB CSR
    uint2* sedge  = (uint2*)(ws + 7143424);        // 196*8192*8 = 12.85 MB (dead after part2)
    short* aggx   = (short*)(ws + 7143424);        // 12.8 MB, overlays sedge
    short* xb     = (short*)(ws + 19988480);       // 12.8 MB bf16(x) unscaled
    short* h2     = (short*)(ws + 32788480);       // 6.4 MB bf16

    // one memset covers coarseCursor + cntg (adjacent)
    hipMemsetAsync(ws, 0, 1024 + N_NODES * 4, stream);

    part1_pack_prep_kernel<<<NPB + NPACK + NPREP, 256, 0, stream>>>(
        srcp, dstp, coarseCursor, cntg, sedge, W1, W2, Bp1, Bp2, x, xb, N_EDGES);
    part2_kernel<<<NPART, 256, 0, stream>>>(sedge, coarseCursor, cntg, offs, dis, ssrc, N_NODES);
    agg1_kernel<<<(N_NODES + 3) / 4, 256, 0, stream>>>(xb, ssrc, offs, cntg, dis, aggx, N_NODES);
    gemm_fused_kernel<<<(N_NODES + 63) / 64, 256, 0, stream>>>(aggx, Bp1, Bp2, b1, dis,
                                                               h2, N_NODES);
    agg2_kernel<<<(N_NODES + 3) / 4, 256, 0, stream>>>(h2, ssrc, offs, cntg, dis, b2, out, N_NODES);
}